// Round 9
// baseline (375.151 us; speedup 1.0000x reference)
//
#include <hip/hip_runtime.h>
#include <math.h>

// ---------------------------------------------------------------------------
// GCN forward: gcn_norm (self-loops) -> [GEMM + CSR-aggregate + bias + relu] x2
//              -> segment_max pool (fused into agg2 via int atomicMax)
//              -> small FC.
// R5: GEMM1 = split-bf16 MFMA. R7: h1/h2 stored bf16.
// R8: aggs use half-wave edge pairing -> 1 VMEM inst/edge (was 2):
//     one gather instruction = 2 edges (32 lanes x uint2/uint each);
//     csr entries via broadcast float4 (2 entries/inst). CSR ranges
//     even-aligned via padded scan. Cross-half combine = shfl_xor(32).
// ---------------------------------------------------------------------------

typedef __attribute__((ext_vector_type(8))) short bfrag;   // 8 bf16 (4 VGPRs)
typedef __attribute__((ext_vector_type(4))) float ffrag;   // MFMA accumulator

__device__ inline void bf16split(float f, short& hi, short& lo) {
    unsigned u = __float_as_uint(f);
    unsigned r = u + 0x7fffu + ((u >> 16) & 1u);            // RNE to bf16
    unsigned short h = (unsigned short)(r >> 16);
    float hf = __uint_as_float(((unsigned)h) << 16);
    float lf = f - hf;
    unsigned ul = __float_as_uint(lf);
    unsigned rl = ul + 0x7fffu + ((ul >> 16) & 1u);
    hi = (short)h;
    lo = (short)(rl >> 16);
}

__device__ inline unsigned short f2bf(float f) {
    unsigned u = __float_as_uint(f);
    unsigned r = u + 0x7fffu + ((u >> 16) & 1u);            // RNE
    return (unsigned short)(r >> 16);
}

__device__ inline float bfl(unsigned u) { return __uint_as_float(u << 16); }
__device__ inline float bfh(unsigned u) { return __uint_as_float(u & 0xffff0000u); }

__global__ __launch_bounds__(256) void k_zero(int* __restrict__ cnt, int* __restrict__ pool,
                                              int n1, int n2) {
    int i = blockIdx.x * 256 + threadIdx.x;
    if (i < n1) cnt[i] = 0;
    if (i < n2) pool[i] = 0;
}

__global__ __launch_bounds__(256) void k_count(const int* __restrict__ ei, int* __restrict__ cnt,
                                               int E) {
    int e = blockIdx.x * 256 + threadIdx.x;
    if (e < E) atomicAdd(&cnt[ei[E + e]], 1);
}

__global__ __launch_bounds__(256) void k_dis(const int* __restrict__ cnt, float* __restrict__ dis,
                                             int N) {
    int v = blockIdx.x * 256 + threadIdx.x;
    if (v < N) dis[v] = 1.0f / sqrtf((float)(cnt[v] + 1));  // +1 self-loop
}

// scan over EVEN-PADDED counts -> every node's CSR range starts at even index
__global__ __launch_bounds__(1024) void k_scan_block(const int* __restrict__ cnt,
                                                     int* __restrict__ rowptr,
                                                     int* __restrict__ bsum, int N) {
    __shared__ int lds[1024];
    int t = threadIdx.x;
    int i = blockIdx.x * 1024 + t;
    int val = (i < N) ? ((cnt[i] + 1) & ~1) : 0;
    lds[t] = val;
    __syncthreads();
    for (int off = 1; off < 1024; off <<= 1) {
        int u = (t >= off) ? lds[t - off] : 0;
        __syncthreads();
        lds[t] += u;
        __syncthreads();
    }
    if (i < N) rowptr[i] = lds[t] - val;  // exclusive within block
    if (t == 1023) bsum[blockIdx.x] = lds[1023];
}

__global__ __launch_bounds__(1024) void k_scan_tot(const int* __restrict__ bsum,
                                                   int* __restrict__ bsum2, int nb) {
    __shared__ int lds[1024];
    int t = threadIdx.x;
    int val = (t < nb) ? bsum[t] : 0;
    lds[t] = val;
    __syncthreads();
    for (int off = 1; off < 1024; off <<= 1) {
        int u = (t >= off) ? lds[t - off] : 0;
        __syncthreads();
        lds[t] += u;
        __syncthreads();
    }
    if (t < nb) bsum2[t] = lds[t] - val;  // exclusive
}

__global__ __launch_bounds__(256) void k_scan_add(int* __restrict__ rowptr, int* __restrict__ cursor,
                                                  const int* __restrict__ bsum2, int N) {
    int i = blockIdx.x * 256 + threadIdx.x;
    if (i < N) {
        int r = rowptr[i] + bsum2[i >> 10];
        rowptr[i] = r;
        cursor[i] = r;
    }
}

// packed CSR entry: .x = src index (int bits), .y = edge weight
__global__ __launch_bounds__(256) void k_fill(const int* __restrict__ ei,
                                              const float* __restrict__ dis,
                                              int* __restrict__ cursor,
                                              float2* __restrict__ csr, int E) {
    int e = blockIdx.x * 256 + threadIdx.x;
    if (e >= E) return;
    int r = ei[e];
    int c = ei[E + e];
    int p = atomicAdd(&cursor[c], 1);
    csr[p] = make_float2(__int_as_float(r), dis[r] * dis[c]);
}

// Pre-split W1 (256x128 fp32) into k-major bf16 hi/lo: Wt[col][k] (col=0..127).
__global__ __launch_bounds__(256) void k_wsplit(const float* __restrict__ W,
                                                short* __restrict__ wt_hi,
                                                short* __restrict__ wt_lo) {
    int i = blockIdx.x * 256 + threadIdx.x;
    if (i >= 256 * 128) return;
    int k = i >> 7, c = i & 127;
    short hi, lo;
    bf16split(W[i], hi, lo);
    wt_hi[c * 256 + k] = hi;
    wt_lo[c * 256 + k] = lo;
}

// ---------------------------------------------------------------------------
// GEMM1 via MFMA: h1b[M x 128] (bf16) = A[M x 256] @ W1, split-bf16.
// ---------------------------------------------------------------------------
__global__ __launch_bounds__(256) void k_gemm1_mfma(const float* __restrict__ A,
                                                    const short* __restrict__ wt_hi,
                                                    const short* __restrict__ wt_lo,
                                                    unsigned short* __restrict__ C, int M) {
    constexpr int KD = 256;
    __shared__ short Ah[64][40];
    __shared__ short Al[64][40];

    const int t = threadIdx.x;
    const int lane = t & 63;
    const int wid = t >> 6;      // 0..3
    const int wr = wid >> 1;     // wave row: rows wr*32..+31
    const int wc = wid & 1;      // wave col: cols wc*64..+63
    const int row0 = blockIdx.x * 64;
    const int lrow = lane & 15;
    const int lkg = lane >> 4;

    ffrag acc[2][4];
#pragma unroll
    for (int mr = 0; mr < 2; mr++)
#pragma unroll
        for (int nr = 0; nr < 4; nr++)
#pragma unroll
            for (int q = 0; q < 4; q++) acc[mr][nr][q] = 0.f;

    for (int kc = 0; kc < KD; kc += 32) {
#pragma unroll
        for (int i = 0; i < 2; i++) {
            int s = t * 2 + i;
            int m = s >> 3;           // row in tile
            int kq = s & 7;           // float4 index in k-chunk
            int r = row0 + m;
            float4 v = make_float4(0.f, 0.f, 0.f, 0.f);
            if (r < M) v = *(const float4*)&A[(size_t)r * KD + kc + kq * 4];
            short4 sh, sl;
            bf16split(v.x, sh.x, sl.x);
            bf16split(v.y, sh.y, sl.y);
            bf16split(v.z, sh.z, sl.z);
            bf16split(v.w, sh.w, sl.w);
            *(short4*)&Ah[m][kq * 4] = sh;
            *(short4*)&Al[m][kq * 4] = sl;
        }
        __syncthreads();

        bfrag ahi[2], alo[2];
#pragma unroll
        for (int mr = 0; mr < 2; mr++) {
            int arow = wr * 32 + mr * 16 + lrow;
            ahi[mr] = *(const bfrag*)&Ah[arow][lkg * 8];
            alo[mr] = *(const bfrag*)&Al[arow][lkg * 8];
        }
#pragma unroll
        for (int nr = 0; nr < 4; nr++) {
            int col = wc * 64 + nr * 16 + lrow;
            const size_t boff = (size_t)col * 256 + kc + lkg * 8;
            bfrag bhi = *(const bfrag*)&wt_hi[boff];
            bfrag blo = *(const bfrag*)&wt_lo[boff];
#pragma unroll
            for (int mr = 0; mr < 2; mr++) {
                acc[mr][nr] = __builtin_amdgcn_mfma_f32_16x16x32_bf16(ahi[mr], bhi, acc[mr][nr], 0, 0, 0);
                acc[mr][nr] = __builtin_amdgcn_mfma_f32_16x16x32_bf16(ahi[mr], blo, acc[mr][nr], 0, 0, 0);
                acc[mr][nr] = __builtin_amdgcn_mfma_f32_16x16x32_bf16(alo[mr], bhi, acc[mr][nr], 0, 0, 0);
            }
        }
        __syncthreads();
    }

#pragma unroll
    for (int mr = 0; mr < 2; mr++)
#pragma unroll
        for (int nr = 0; nr < 4; nr++)
#pragma unroll
            for (int q = 0; q < 4; q++) {
                int rr = row0 + wr * 32 + mr * 16 + lkg * 4 + q;
                int cc = wc * 64 + nr * 16 + lrow;
                if (rr < M) C[(size_t)rr * 128 + cc] = f2bf(acc[mr][nr][q]);
            }
}

// ---------------------------------------------------------------------------
// fp32 VALU GEMM (layer 2), bf16 output: h2b[M x 64] = a1[M x 128] @ W2
// ---------------------------------------------------------------------------
__global__ __launch_bounds__(256) void k_gemm2(const float* __restrict__ A,
                                               const float* __restrict__ W,
                                               unsigned short* __restrict__ C, int M) {
    constexpr int KDIM = 128, NOUT = 64, BM = 64, BK = 32;
    __shared__ float As[BK][BM + 4];
    __shared__ float Ws[BK][NOUT];

    const int t = threadIdx.x;
    const int tx = t & 15;
    const int ty = t >> 4;
    const int row0 = blockIdx.x * BM;

    float acc[4][4];
#pragma unroll
    for (int r = 0; r < 4; r++)
#pragma unroll
        for (int c = 0; c < 4; c++) acc[r][c] = 0.f;

    for (int kc = 0; kc < KDIM; kc += BK) {
#pragma unroll
        for (int i = 0; i < 2; i++) {
            int s = t * 2 + i;
            int m = s >> 3;
            int kq = s & 7;
            int r = row0 + m;
            float4 v = make_float4(0.f, 0.f, 0.f, 0.f);
            if (r < M) v = *(const float4*)&A[(size_t)r * KDIM + kc + kq * 4];
            As[kq * 4 + 0][m] = v.x;
            As[kq * 4 + 1][m] = v.y;
            As[kq * 4 + 2][m] = v.z;
            As[kq * 4 + 3][m] = v.w;
        }
#pragma unroll
        for (int i = 0; i < 2; i++) {
            int s = t + i * 256;
            int k = s / 16;
            int c4 = s % 16;
            *(float4*)&Ws[k][c4 * 4] = *(const float4*)&W[(size_t)(kc + k) * NOUT + c4 * 4];
        }
        __syncthreads();

#pragma unroll
        for (int k = 0; k < BK; k++) {
            float4 a = *(const float4*)&As[k][ty * 4];
            float4 w0 = *(const float4*)&Ws[k][tx * 4];
            const float* ap = (const float*)&a;
            const float* w0p = (const float*)&w0;
#pragma unroll
            for (int r = 0; r < 4; r++)
#pragma unroll
                for (int c = 0; c < 4; c++) acc[r][c] += ap[r] * w0p[c];
        }
        __syncthreads();
    }

#pragma unroll
    for (int r = 0; r < 4; r++) {
        int rr = row0 + ty * 4 + r;
        if (rr < M) {
            ushort4 o;
            o.x = f2bf(acc[r][0]);
            o.y = f2bf(acc[r][1]);
            o.z = f2bf(acc[r][2]);
            o.w = f2bf(acc[r][3]);
            *(ushort4*)&C[(size_t)rr * NOUT + tx * 4] = o;
        }
    }
}

// Layer-1 aggregate, half-wave edge pairing: one wave/node; lanes 0-31 = even
// edges, lanes 32-63 = odd edges; each half-lane gathers uint2 (4 bf16 feats)
// of a 256B row. 1 VMEM inst per edge. out = relu(agg + b), fp32.
__global__ __launch_bounds__(256) void k_agg1(const uint2* __restrict__ h,   // [N][32]
                                              const int* __restrict__ rowptr,
                                              const int* __restrict__ cnt,
                                              const float4* __restrict__ csr2,
                                              const float* __restrict__ dis,
                                              const float* __restrict__ b,
                                              float* __restrict__ out, int N) {
    int wave = (blockIdx.x * 256 + threadIdx.x) >> 6;
    int lane = threadIdx.x & 63;
    if (wave >= N) return;
    const int v = wave;
    const int half = lane >> 5;
    const int hl = lane & 31;
    float d = dis[v];
    float selfw = half ? 0.f : d * d;
    uint2 sv = h[(size_t)v * 32 + hl];
    float a0 = selfw * bfl(sv.x), a1 = selfw * bfh(sv.x);
    float a2 = selfw * bfl(sv.y), a3 = selfw * bfh(sv.y);
    int s0 = rowptr[v], s1 = s0 + cnt[v];
    for (int j = s0; j < s1; j += 8) {
        int   uu[4];
        float ww[4];
#pragma unroll
        for (int q = 0; q < 4; q++) {
            float4 ce = csr2[(j >> 1) + q];       // entries j+2q, j+2q+1
            int jj = j + 2 * q + half;
            bool ok = jj < s1;
            float ux = half ? ce.z : ce.x;
            float wx = half ? ce.w : ce.y;
            uu[q] = ok ? __float_as_int(ux) : 0;
            ww[q] = ok ? wx : 0.f;
        }
        uint2 g[4];
#pragma unroll
        for (int q = 0; q < 4; q++) g[q] = h[(size_t)uu[q] * 32 + hl];
#pragma unroll
        for (int q = 0; q < 4; q++) {
            a0 += ww[q] * bfl(g[q].x);
            a1 += ww[q] * bfh(g[q].x);
            a2 += ww[q] * bfl(g[q].y);
            a3 += ww[q] * bfh(g[q].y);
        }
    }
    // combine the two edge-halves (same features, disjoint edges)
    a0 += __shfl_xor(a0, 32);
    a1 += __shfl_xor(a1, 32);
    a2 += __shfl_xor(a2, 32);
    a3 += __shfl_xor(a3, 32);
    if (half == 0) {
        float4 bb = *(const float4*)&b[hl * 4];
        float4 o;
        o.x = fmaxf(a0 + bb.x, 0.f);
        o.y = fmaxf(a1 + bb.y, 0.f);
        o.z = fmaxf(a2 + bb.z, 0.f);
        o.w = fmaxf(a3 + bb.w, 0.f);
        *(float4*)&out[(size_t)v * 128 + hl * 4] = o;
    }
}

// Layer-2 aggregate + pool, half-wave edge pairing: gathers uint (2 bf16
// feats) of a 128B row; fused bias+relu+graph atomicMax.
__global__ __launch_bounds__(256) void k_agg2_pool(const unsigned int* __restrict__ h, // [N][32]
                                                   const int* __restrict__ rowptr,
                                                   const int* __restrict__ cnt,
                                                   const float4* __restrict__ csr2,
                                                   const float* __restrict__ dis,
                                                   const float* __restrict__ b,
                                                   const int* __restrict__ batch,
                                                   float* __restrict__ pool, int N) {
    int wave = (blockIdx.x * 256 + threadIdx.x) >> 6;
    int lane = threadIdx.x & 63;
    if (wave >= N) return;
    const int v = wave;
    const int half = lane >> 5;
    const int hl = lane & 31;
    float d = dis[v];
    float selfw = half ? 0.f : d * d;
    unsigned sv = h[(size_t)v * 32 + hl];
    float a0 = selfw * bfl(sv), a1 = selfw * bfh(sv);
    int s0 = rowptr[v], s1 = s0 + cnt[v];
    for (int j = s0; j < s1; j += 8) {
        int   uu[4];
        float ww[4];
#pragma unroll
        for (int q = 0; q < 4; q++) {
            float4 ce = csr2[(j >> 1) + q];
            int jj = j + 2 * q + half;
            bool ok = jj < s1;
            float ux = half ? ce.z : ce.x;
            float wx = half ? ce.w : ce.y;
            uu[q] = ok ? __float_as_int(ux) : 0;
            ww[q] = ok ? wx : 0.f;
        }
        unsigned g[4];
#pragma unroll
        for (int q = 0; q < 4; q++) g[q] = h[(size_t)uu[q] * 32 + hl];
#pragma unroll
        for (int q = 0; q < 4; q++) {
            a0 += ww[q] * bfl(g[q]);
            a1 += ww[q] * bfh(g[q]);
        }
    }
    a0 += __shfl_xor(a0, 32);
    a1 += __shfl_xor(a1, 32);
    if (half == 0) {
        float2 bb = *(const float2*)&b[hl * 2];
        float v0 = fmaxf(a0 + bb.x, 0.f);
        float v1 = fmaxf(a1 + bb.y, 0.f);
        int g = batch[v];
        // vals >= 0 so float bits order as signed ints; pool zero-initialized.
        atomicMax((int*)&pool[(size_t)g * 64 + hl * 2], __float_as_int(v0));
        atomicMax((int*)&pool[(size_t)g * 64 + hl * 2 + 1], __float_as_int(v1));
    }
}

__global__ __launch_bounds__(256) void k_fc(const float* __restrict__ pool,
                                            const float* __restrict__ Wfc,
                                            const float* __restrict__ bfc,
                                            float* __restrict__ out, int G) {
    int t = blockIdx.x * 256 + threadIdx.x;
    if (t >= G * 10) return;
    int g = t / 10, o = t % 10;
    float acc = bfc[o];
#pragma unroll
    for (int f = 0; f < 64; f++) acc += pool[g * 64 + f] * Wfc[f * 10 + o];
    out[t] = acc;
}

extern "C" void kernel_launch(void* const* d_in, const int* in_sizes, int n_in,
                              void* d_out, int out_size, void* d_ws, size_t ws_size,
                              hipStream_t stream) {
    const float* x   = (const float*)d_in[0];
    const int*   ei  = (const int*)d_in[1];
    const int*   bat = (const int*)d_in[2];
    const float* W1  = (const float*)d_in[3];
    const float* b1  = (const float*)d_in[4];
    const float* W2  = (const float*)d_in[5];
    const float* b2  = (const float*)d_in[6];
    const float* Wfc = (const float*)d_in[7];
    const float* bfc = (const float*)d_in[8];
    float* out = (float*)d_out;

    const int N = in_sizes[2];          // 50000
    const int E = in_sizes[1] / 2;      // 800000
    const int G = out_size / 10;        // 128

    // workspace layout (256B aligned)
    char* ws = (char*)d_ws;
    size_t off = 0;
    auto alloc = [&](size_t bytes) -> char* {
        char* p = ws + off;
        off = (off + bytes + 255) & ~(size_t)255;
        return p;
    };
    int*    cnt    = (int*)alloc((size_t)N * 4);
    float*  dis    = (float*)alloc((size_t)N * 4);
    int*    rowptr = (int*)alloc((size_t)(N + 1) * 4);
    int*    cursor = (int*)alloc((size_t)N * 4);
    int*    bsum   = (int*)alloc(1024 * 4);
    int*    bsum2  = (int*)alloc(1024 * 4);
    float2* csr    = (float2*)alloc((size_t)(E + N + 8) * 8);  // even-aligned ranges
    unsigned short* h1b = (unsigned short*)alloc((size_t)N * 128 * 2);
    float*  a1     = (float*)alloc((size_t)N * 128 * 4);
    unsigned short* h2b = (unsigned short*)alloc((size_t)N * 64 * 2);
    float*  pool   = (float*)alloc((size_t)G * 64 * 4);
    short*  wt_hi  = (short*)alloc(128 * 256 * 2);
    short*  wt_lo  = (short*)alloc(128 * 256 * 2);
    (void)ws_size; (void)n_in;

    const int nb = (N + 1023) / 1024;

    // ---- gcn_norm + CSR build (+ W1 split) ----
    {
        int zmax = N > G * 64 ? N : G * 64;
        k_zero<<<(zmax + 255) / 256, 256, 0, stream>>>(cnt, (int*)pool, N, G * 64);
    }
    k_wsplit<<<128, 256, 0, stream>>>(W1, wt_hi, wt_lo);
    k_count<<<(E + 255) / 256, 256, 0, stream>>>(ei, cnt, E);
    k_dis<<<(N + 255) / 256, 256, 0, stream>>>(cnt, dis, N);
    k_scan_block<<<nb, 1024, 0, stream>>>(cnt, rowptr, bsum, N);
    k_scan_tot<<<1, 1024, 0, stream>>>(bsum, bsum2, nb);
    k_scan_add<<<(N + 255) / 256, 256, 0, stream>>>(rowptr, cursor, bsum2, N);
    k_fill<<<(E + 255) / 256, 256, 0, stream>>>(ei, dis, cursor, csr, E);

    // ---- layer 1 (MFMA split-bf16 GEMM -> bf16 h1; paired bf16 gathers) ----
    k_gemm1_mfma<<<(N + 63) / 64, 256, 0, stream>>>(x, wt_hi, wt_lo, h1b, N);
    k_agg1<<<(N * 64 + 255) / 256, 256, 0, stream>>>((const uint2*)h1b, rowptr, cnt,
                                                     (const float4*)csr, dis, b1, a1, N);

    // ---- layer 2 (fp32 GEMM -> bf16 h2; paired bf16 gathers; fused pool) ----
    k_gemm2<<<(N + 63) / 64, 256, 0, stream>>>(a1, W2, h2b, N);
    k_agg2_pool<<<(N * 64 + 255) / 256, 256, 0, stream>>>((const unsigned int*)h2b, rowptr, cnt,
                                                          (const float4*)csr, dis, b2, bat,
                                                          pool, N);

    // ---- FC head ----
    k_fc<<<(G * 10 + 255) / 256, 256, 0, stream>>>(pool, Wfc, bfc, out, G);
}